// Round 14
// baseline (798.464 us; speedup 1.0000x reference)
//
#include <hip/hip_runtime.h>
#include <hip/hip_fp16.h>

#define TILE 64

// ---------------------------------------------------------------------------
// K1: HTh[n*B+b] = fp16(pred_p*p_scale+p_mean+elev)   (transposed)
//     TD [n*B+b] = fp16(true_d*d_scale+d_mean)        (transposed)
// ---------------------------------------------------------------------------
__global__ void k_build_ht(const float* __restrict__ pred_p,
                           const float* __restrict__ p_scale,
                           const float* __restrict__ p_mean,
                           const float* __restrict__ elev,
                           const float* __restrict__ true_d,
                           const float* __restrict__ d_scale,
                           const float* __restrict__ d_mean,
                           __half* __restrict__ HTh,
                           __half* __restrict__ TD,
                           int B, int N) {
    __shared__ __align__(16) float tile[TILE][TILE + 2];
    const int n0 = blockIdx.x * TILE;
    const int b0 = blockIdx.y * TILE;
    const int tn = threadIdx.x % TILE;
    const int tw = threadIdx.x / TILE;
    const int c  = threadIdx.x & 31;
    const int rg = threadIdx.x >> 5;
    const int n = n0 + tn;

    // ---- pass 1: HT ----
    {
        float sc = 0.f, mn = 0.f, el = 0.f;
        if (n < N) { sc = p_scale[n]; mn = p_mean[n]; el = elev[n]; }
        #pragma unroll
        for (int i = 0; i < TILE / 4; ++i) {
            const int bl = i * 4 + tw;
            float v = 0.f;
            if (n < N) v = pred_p[(size_t)(b0 + bl) * N + n] * sc + mn + el;
            tile[tn][bl] = v;
        }
        __syncthreads();
        #pragma unroll
        for (int i = 0; i < 8; ++i) {
            const int nl = i * 8 + rg;
            const int nn = n0 + nl;
            if (nn < N) {
                const float2 f = *reinterpret_cast<const float2*>(&tile[nl][2 * c]);
                reinterpret_cast<__half2*>(HTh + (size_t)nn * B + b0)[c] =
                    __floats2half2_rn(f.x, f.y);
            }
        }
    }
    __syncthreads();
    // ---- pass 2: TD ----
    {
        float sc = 0.f, mn = 0.f;
        if (n < N) { sc = d_scale[n]; mn = d_mean[n]; }
        #pragma unroll
        for (int i = 0; i < TILE / 4; ++i) {
            const int bl = i * 4 + tw;
            float v = 0.f;
            if (n < N) v = true_d[(size_t)(b0 + bl) * N + n] * sc + mn;
            tile[tn][bl] = v;
        }
        __syncthreads();
        #pragma unroll
        for (int i = 0; i < 8; ++i) {
            const int nl = i * 8 + rg;
            const int nn = n0 + nl;
            if (nn < N) {
                const float2 f = *reinterpret_cast<const float2*>(&tile[nl][2 * c]);
                reinterpret_cast<__half2*>(TD + (size_t)nn * B + b0)[c] =
                    __floats2half2_rn(f.x, f.y);
            }
        }
    }
}

// ---------------------------------------------------------------------------
// CSR build: hist -> scans -> fill.  inc[slot] = (edge<<1) | is_dst.
// ---------------------------------------------------------------------------
__global__ void k_hist(const int* __restrict__ nodes, int* __restrict__ deg, int M) {
    const int i = blockIdx.x * 256 + threadIdx.x;
    if (i < M) atomicAdd(&deg[nodes[i]], 1);
}

__global__ void k_scan1(const int* __restrict__ deg, int* __restrict__ bsum, int N) {
    __shared__ int s[256];
    const int i = blockIdx.x * 256 + threadIdx.x;
    s[threadIdx.x] = (i < N) ? deg[i] : 0;
    __syncthreads();
    #pragma unroll
    for (int off = 128; off >= 1; off >>= 1) {
        if (threadIdx.x < off) s[threadIdx.x] += s[threadIdx.x + off];
        __syncthreads();
    }
    if (threadIdx.x == 0) bsum[blockIdx.x] = s[0];
}

__global__ void k_scan2(int* __restrict__ bsum, int nb) {   // 1 block
    __shared__ int s[256];
    const int t = threadIdx.x;
    const int v = (t < nb) ? bsum[t] : 0;
    s[t] = v;
    __syncthreads();
    #pragma unroll
    for (int off = 1; off < 256; off <<= 1) {
        const int tmp = (t >= off) ? s[t - off] : 0;
        __syncthreads();
        s[t] += tmp;
        __syncthreads();
    }
    if (t < nb) bsum[t] = s[t] - v;
}

__global__ void k_scan3(const int* __restrict__ deg, const int* __restrict__ bsum,
                        int* __restrict__ offsets, int* __restrict__ cursor, int N) {
    __shared__ int s[256];
    const int t = threadIdx.x;
    const int i = blockIdx.x * 256 + t;
    const int v = (i < N) ? deg[i] : 0;
    s[t] = v;
    __syncthreads();
    #pragma unroll
    for (int off = 1; off < 256; off <<= 1) {
        const int tmp = (t >= off) ? s[t - off] : 0;
        __syncthreads();
        s[t] += tmp;
        __syncthreads();
    }
    const int excl = s[t] - v + bsum[blockIdx.x];
    if (i < N) { offsets[i] = excl; cursor[i] = excl; }
    if (i == N - 1) offsets[N] = excl + v;
}

__global__ void k_fill(const int* __restrict__ esrc, const int* __restrict__ edst,
                       int* __restrict__ cursor, int* __restrict__ inc, int E) {
    const int e = blockIdx.x * 256 + threadIdx.x;
    if (e < E) {
        const int ps = atomicAdd(&cursor[esrc[e]], 1);
        inc[ps] = (e << 1);            // outflow: -Q
        const int pd = atomicAdd(&cursor[edst[e]], 1);
        inc[pd] = (e << 1) | 1;        // inflow: +Q
    }
}

// ---------------------------------------------------------------------------
// K2: per (edge-tile, batch-slab): Q -> LINEAR fp16 store into QT[E][256]
// (no atomics); head loss via hoisted fp16 HT gathers.  (= round-13 kernel)
// ---------------------------------------------------------------------------
__global__ void k_edges(const float* __restrict__ pred_f,
                        const float* __restrict__ f_scale,
                        const float* __restrict__ f_mean,
                        const float* __restrict__ Rcoef,
                        const int* __restrict__ esrc,
                        const int* __restrict__ edst,
                        const __half* __restrict__ HTh,   // [N][B] fp16
                        __half* __restrict__ QT,          // [E][B] fp16
                        double* __restrict__ head_accum,
                        int B, int E) {
    __shared__ __align__(16) float qt[TILE][TILE + 2];
    __shared__ double wsum[4];
    const int e0 = blockIdx.x * TILE;
    const int b0 = blockIdx.y * TILE;
    const int te = threadIdx.x % TILE;
    const int tw = threadIdx.x / TILE;

    const int e = e0 + te;
    const float fs = f_scale[e];
    const float fm = f_mean[e];
    #pragma unroll
    for (int i = 0; i < TILE / 4; ++i) {
        const int bl = i * 4 + tw;
        qt[te][bl] = pred_f[(size_t)(b0 + bl) * E + e] * fs + fm;
    }
    __syncthreads();

    const int bl = te;
    const __half* HTb = HTh + b0 + bl;

    int   sarr[16], darr[16];
    float hs[16], hd[16];
    #pragma unroll
    for (int j = 0; j < 16; ++j) {
        const int ee = e0 + tw * 16 + j;
        sarr[j] = esrc[ee];
        darr[j] = edst[ee];
        hs[j] = __half2float(HTb[(size_t)sarr[j] * B]);
        hd[j] = __half2float(HTb[(size_t)darr[j] * B]);
    }

    const int sel = bl >> 5;
    const int pc  = bl & 31;
    #pragma unroll
    for (int k = 0; k < 8; ++k) {
        const int el = tw * 16 + 2 * k + sel;
        const float2 q01 = *reinterpret_cast<const float2*>(&qt[el][2 * pc]);
        const __half2 h = __floats2half2_rn(q01.x, q01.y);
        *reinterpret_cast<__half2*>(
            (char*)QT + (size_t)(e0 + el) * B * 2 + (size_t)b0 * 2 + pc * 4) = h;
    }

    double head = 0.0;
    #pragma unroll
    for (int j = 0; j < 16; ++j) {
        const int el = tw * 16 + j;
        const int ee = e0 + el;
        const float q = qt[el][bl];
        const float aq = fabsf(q);
        const float pw = exp2f(0.852f * __log2f(aq));   // |q|^0.852
        const float fr = Rcoef[ee] * q * pw;
        const float t = (hs[j] - hd[j]) - fr;
        head += (double)t * (double)t;
    }

    #pragma unroll
    for (int off = 32; off >= 1; off >>= 1)
        head += __shfl_down(head, off, 64);
    if ((threadIdx.x & 63) == 0) wsum[threadIdx.x >> 6] = head;
    __syncthreads();
    if (threadIdx.x == 0)
        atomicAdd(head_accum, wsum[0] + wsum[1] + wsum[2] + wsum[3]);
}

// ---------------------------------------------------------------------------
// K3: ONE WAVE PER NODE.  q_net for all 256 batches = sum over the node's
// CSR entries of signed QT rows; each entry is ONE wave-load (uint2/lane =
// 512B).  8 entries hoisted/in flight.  Mass loss fused via TD row.
// No LDS, no barriers, no atomics except 1 f64 per wave.
// ---------------------------------------------------------------------------
__global__ __launch_bounds__(256) void k_nodemass(
        const __half* __restrict__ QT,      // [E][256]
        const __half* __restrict__ TD,      // [N][256]
        const int* __restrict__ offsets,    // [N+1]
        const int* __restrict__ inc,        // [2E]
        double* __restrict__ mass_accum,
        int N) {
    const int w = threadIdx.x >> 6;
    const int lane = threadIdx.x & 63;
    const int n = blockIdx.x * 4 + w;

    double m = 0.0;
    if (n < N) {
        // hoist TD row (independent of the gather chain)
        const uint2 tdr = *reinterpret_cast<const uint2*>(
            (const char*)TD + (size_t)n * 512 + (size_t)lane * 8);

        const int beg = offsets[n];
        const int end = offsets[n + 1];

        float qn0 = 0.f, qn1 = 0.f, qn2 = 0.f, qn3 = 0.f;
        for (int k = beg; k < end; k += 8) {
            int   ivv[8];
            float sg[8];
            uint2 vv[8];
            #pragma unroll
            for (int u = 0; u < 8; ++u) {
                const int kk = (k + u < end) ? (k + u) : (end - 1);
                ivv[u] = inc[kk];                       // wave-uniform bcast
                sg[u] = (k + u < end) ? ((ivv[u] & 1) ? 1.f : -1.f) : 0.f;
                vv[u] = *reinterpret_cast<const uint2*>(
                    (const char*)QT + (size_t)(ivv[u] >> 1) * 512
                                    + (size_t)lane * 8);
            }
            #pragma unroll
            for (int u = 0; u < 8; ++u) {
                const __half2 a = *reinterpret_cast<const __half2*>(&vv[u].x);
                const __half2 b = *reinterpret_cast<const __half2*>(&vv[u].y);
                const float2 fa = __half22float2(a);
                const float2 fb = __half22float2(b);
                qn0 += sg[u] * fa.x; qn1 += sg[u] * fa.y;
                qn2 += sg[u] * fb.x; qn3 += sg[u] * fb.y;
            }
        }

        const __half2 d01 = *reinterpret_cast<const __half2*>(&tdr.x);
        const __half2 d23 = *reinterpret_cast<const __half2*>(&tdr.y);
        const float2 f01 = __half22float2(d01);
        const float2 f23 = __half22float2(d23);
        const float t0 = qn0 - f01.x;
        const float t1 = qn1 - f01.y;
        const float t2 = qn2 - f23.x;
        const float t3 = qn3 - f23.y;
        m = (double)t0 * t0 + (double)t1 * t1
          + (double)t2 * t2 + (double)t3 * t3;
    }

    #pragma unroll
    for (int off = 32; off >= 1; off >>= 1)
        m += __shfl_down(m, off, 64);
    if (lane == 0 && n < N)
        atomicAdd(mass_accum, m);
}

// ---------------------------------------------------------------------------
__global__ void k_final(const double* __restrict__ accum,
                        float* __restrict__ out,
                        double inv_mass_count, double inv_head_count) {
    out[0] = (float)(accum[0] * inv_mass_count);
    out[1] = (float)(accum[1] * inv_head_count);
}

static inline size_t align256s(size_t x) { return (x + 255) & ~(size_t)255; }

extern "C" void kernel_launch(void* const* d_in, const int* in_sizes, int n_in,
                              void* d_out, int out_size, void* d_ws, size_t ws_size,
                              hipStream_t stream) {
    const float* pred_p  = (const float*)d_in[0];
    const float* pred_f  = (const float*)d_in[1];
    const float* true_d  = (const float*)d_in[2];
    const float* p_mean  = (const float*)d_in[3];
    const float* p_scale = (const float*)d_in[4];
    const float* f_mean  = (const float*)d_in[5];
    const float* f_scale = (const float*)d_in[6];
    const float* d_mean  = (const float*)d_in[7];
    const float* d_scale = (const float*)d_in[8];
    const float* elev    = (const float*)d_in[9];
    const float* Rcoef   = (const float*)d_in[10];
    const int*   eidx    = (const int*)d_in[11];

    const int N = in_sizes[3];              // 50000
    const int E = in_sizes[10];             // 128000
    const int B = in_sizes[0] / N;          // 256

    const int* esrc = eidx;
    const int* edst = eidx + E;

    // workspace layout
    char* ws = (char*)d_ws;
    size_t off = 0;
    __half* HTh   = (__half*)(ws + off); off = align256s(off + (size_t)N * B * 2);
    __half* TD    = (__half*)(ws + off); off = align256s(off + (size_t)N * B * 2);
    __half* QT    = (__half*)(ws + off); off = align256s(off + (size_t)E * B * 2);
    int* incarr   = (int*)(ws + off);    off = align256s(off + (size_t)2 * E * 4);
    int* offsets  = (int*)(ws + off);    off = align256s(off + (size_t)(N + 1) * 4);
    int* cursor   = (int*)(ws + off);    off = align256s(off + (size_t)N * 4);
    const size_t zero_beg = off;
    int* deg      = (int*)(ws + off);    off = align256s(off + (size_t)N * 4);
    int* bsum     = (int*)(ws + off);    off = align256s(off + 256 * 4);
    double* accum = (double*)(ws + off); off += 2 * sizeof(double);
    const size_t zero_len = off - zero_beg;

    hipMemsetAsync(ws + zero_beg, 0, zero_len, stream);

    const int gn = (N + TILE - 1) / TILE;   // 782
    const int gb = B / TILE;                // 4
    const int ge = E / TILE;                // 2000
    const int nb = (N + 255) / 256;         // 196

    k_hist <<<(2 * E + 255) / 256, 256, 0, stream>>>(eidx, deg, 2 * E);
    k_scan1<<<nb, 256, 0, stream>>>(deg, bsum, N);
    k_scan2<<<1, 256, 0, stream>>>(bsum, nb);
    k_scan3<<<nb, 256, 0, stream>>>(deg, bsum, offsets, cursor, N);
    k_fill <<<(E + 255) / 256, 256, 0, stream>>>(esrc, edst, cursor, incarr, E);

    k_build_ht<<<dim3(gn, gb), 256, 0, stream>>>(pred_p, p_scale, p_mean, elev,
                                                 true_d, d_scale, d_mean,
                                                 HTh, TD, B, N);
    k_edges<<<dim3(ge, gb), 256, 0, stream>>>(pred_f, f_scale, f_mean, Rcoef,
                                              esrc, edst, HTh, QT,
                                              accum + 1, B, E);
    k_nodemass<<<(N + 3) / 4, 256, 0, stream>>>(QT, TD, offsets, incarr,
                                                accum + 0, N);
    k_final<<<1, 1, 0, stream>>>(accum, (float*)d_out,
                                 1.0 / ((double)B * (double)N),
                                 1.0 / ((double)B * (double)E));
}

// Round 16
// 180.956 us; speedup vs baseline: 4.4125x; 4.4125x over previous
//
#include <hip/hip_runtime.h>
#include <hip/hip_fp16.h>

#define TILE 64

// ---------------------------------------------------------------------------
// K1: HTh[n*B+b] = fp16(pred_p*p_scale+p_mean+elev)   (transposed)
//     TD [n*B+b] = fp16(true_d*d_scale+d_mean)        (transposed)
// ---------------------------------------------------------------------------
__global__ void k_build_ht(const float* __restrict__ pred_p,
                           const float* __restrict__ p_scale,
                           const float* __restrict__ p_mean,
                           const float* __restrict__ elev,
                           const float* __restrict__ true_d,
                           const float* __restrict__ d_scale,
                           const float* __restrict__ d_mean,
                           __half* __restrict__ HTh,
                           __half* __restrict__ TD,
                           int B, int N) {
    __shared__ __align__(16) float tile[TILE][TILE + 2];
    const int n0 = blockIdx.x * TILE;
    const int b0 = blockIdx.y * TILE;
    const int tn = threadIdx.x % TILE;
    const int tw = threadIdx.x / TILE;
    const int c  = threadIdx.x & 31;
    const int rg = threadIdx.x >> 5;
    const int n = n0 + tn;

    // ---- pass 1: HT ----
    {
        float sc = 0.f, mn = 0.f, el = 0.f;
        if (n < N) { sc = p_scale[n]; mn = p_mean[n]; el = elev[n]; }
        #pragma unroll
        for (int i = 0; i < TILE / 4; ++i) {
            const int bl = i * 4 + tw;
            float v = 0.f;
            if (n < N) v = pred_p[(size_t)(b0 + bl) * N + n] * sc + mn + el;
            tile[tn][bl] = v;
        }
        __syncthreads();
        #pragma unroll
        for (int i = 0; i < 8; ++i) {
            const int nl = i * 8 + rg;
            const int nn = n0 + nl;
            if (nn < N) {
                const float2 f = *reinterpret_cast<const float2*>(&tile[nl][2 * c]);
                reinterpret_cast<__half2*>(HTh + (size_t)nn * B + b0)[c] =
                    __floats2half2_rn(f.x, f.y);
            }
        }
    }
    __syncthreads();
    // ---- pass 2: TD ----
    {
        float sc = 0.f, mn = 0.f;
        if (n < N) { sc = d_scale[n]; mn = d_mean[n]; }
        #pragma unroll
        for (int i = 0; i < TILE / 4; ++i) {
            const int bl = i * 4 + tw;
            float v = 0.f;
            if (n < N) v = true_d[(size_t)(b0 + bl) * N + n] * sc + mn;
            tile[tn][bl] = v;
        }
        __syncthreads();
        #pragma unroll
        for (int i = 0; i < 8; ++i) {
            const int nl = i * 8 + rg;
            const int nn = n0 + nl;
            if (nn < N) {
                const float2 f = *reinterpret_cast<const float2*>(&tile[nl][2 * c]);
                reinterpret_cast<__half2*>(TD + (size_t)nn * B + b0)[c] =
                    __floats2half2_rn(f.x, f.y);
            }
        }
    }
}

// ---------------------------------------------------------------------------
// CSR build: hist -> scans -> fill.  inc[slot] = (edge<<1) | is_dst.
// ---------------------------------------------------------------------------
__global__ void k_hist(const int* __restrict__ nodes, int* __restrict__ deg, int M) {
    const int i = blockIdx.x * 256 + threadIdx.x;
    if (i < M) atomicAdd(&deg[nodes[i]], 1);
}

__global__ void k_scan1(const int* __restrict__ deg, int* __restrict__ bsum, int N) {
    __shared__ int s[256];
    const int i = blockIdx.x * 256 + threadIdx.x;
    s[threadIdx.x] = (i < N) ? deg[i] : 0;
    __syncthreads();
    #pragma unroll
    for (int off = 128; off >= 1; off >>= 1) {
        if (threadIdx.x < off) s[threadIdx.x] += s[threadIdx.x + off];
        __syncthreads();
    }
    if (threadIdx.x == 0) bsum[blockIdx.x] = s[0];
}

__global__ void k_scan2(int* __restrict__ bsum, int nb) {   // 1 block
    __shared__ int s[256];
    const int t = threadIdx.x;
    const int v = (t < nb) ? bsum[t] : 0;
    s[t] = v;
    __syncthreads();
    #pragma unroll
    for (int off = 1; off < 256; off <<= 1) {
        const int tmp = (t >= off) ? s[t - off] : 0;
        __syncthreads();
        s[t] += tmp;
        __syncthreads();
    }
    if (t < nb) bsum[t] = s[t] - v;
}

__global__ void k_scan3(const int* __restrict__ deg, const int* __restrict__ bsum,
                        int* __restrict__ offsets, int* __restrict__ cursor, int N) {
    __shared__ int s[256];
    const int t = threadIdx.x;
    const int i = blockIdx.x * 256 + t;
    const int v = (i < N) ? deg[i] : 0;
    s[t] = v;
    __syncthreads();
    #pragma unroll
    for (int off = 1; off < 256; off <<= 1) {
        const int tmp = (t >= off) ? s[t - off] : 0;
        __syncthreads();
        s[t] += tmp;
        __syncthreads();
    }
    const int excl = s[t] - v + bsum[blockIdx.x];
    if (i < N) { offsets[i] = excl; cursor[i] = excl; }
    if (i == N - 1) offsets[N] = excl + v;
}

__global__ void k_fill(const int* __restrict__ esrc, const int* __restrict__ edst,
                       int* __restrict__ cursor, int* __restrict__ inc, int E) {
    const int e = blockIdx.x * 256 + threadIdx.x;
    if (e < E) {
        const int ps = atomicAdd(&cursor[esrc[e]], 1);
        inc[ps] = (e << 1);            // outflow: -Q
        const int pd = atomicAdd(&cursor[edst[e]], 1);
        inc[pd] = (e << 1) | 1;        // inflow: +Q
    }
}

// ---------------------------------------------------------------------------
// K2: per (edge-tile, batch-slab): Q -> LINEAR fp16 store into QT[E][256]
// (no atomics); head loss via hoisted fp16 HT gathers.
// Block partial -> PLAIN STORE to headp[block] (no same-address atomics).
// ---------------------------------------------------------------------------
__global__ void k_edges(const float* __restrict__ pred_f,
                        const float* __restrict__ f_scale,
                        const float* __restrict__ f_mean,
                        const float* __restrict__ Rcoef,
                        const int* __restrict__ esrc,
                        const int* __restrict__ edst,
                        const __half* __restrict__ HTh,   // [N][B] fp16
                        __half* __restrict__ QT,          // [E][B] fp16
                        double* __restrict__ headp,       // [gb*ge] partials
                        int B, int E) {
    __shared__ __align__(16) float qt[TILE][TILE + 2];
    __shared__ double wsum[4];
    const int e0 = blockIdx.x * TILE;
    const int b0 = blockIdx.y * TILE;
    const int te = threadIdx.x % TILE;
    const int tw = threadIdx.x / TILE;

    const int e = e0 + te;
    const float fs = f_scale[e];
    const float fm = f_mean[e];
    #pragma unroll
    for (int i = 0; i < TILE / 4; ++i) {
        const int bl = i * 4 + tw;
        qt[te][bl] = pred_f[(size_t)(b0 + bl) * E + e] * fs + fm;
    }
    __syncthreads();

    const int bl = te;
    const __half* HTb = HTh + b0 + bl;

    int   sarr[16], darr[16];
    float hs[16], hd[16];
    #pragma unroll
    for (int j = 0; j < 16; ++j) {
        const int ee = e0 + tw * 16 + j;
        sarr[j] = esrc[ee];
        darr[j] = edst[ee];
        hs[j] = __half2float(HTb[(size_t)sarr[j] * B]);
        hd[j] = __half2float(HTb[(size_t)darr[j] * B]);
    }

    const int sel = bl >> 5;
    const int pc  = bl & 31;
    #pragma unroll
    for (int k = 0; k < 8; ++k) {
        const int el = tw * 16 + 2 * k + sel;
        const float2 q01 = *reinterpret_cast<const float2*>(&qt[el][2 * pc]);
        const __half2 h = __floats2half2_rn(q01.x, q01.y);
        *reinterpret_cast<__half2*>(
            (char*)QT + (size_t)(e0 + el) * B * 2 + (size_t)b0 * 2 + pc * 4) = h;
    }

    double head = 0.0;
    #pragma unroll
    for (int j = 0; j < 16; ++j) {
        const int el = tw * 16 + j;
        const int ee = e0 + el;
        const float q = qt[el][bl];
        const float aq = fabsf(q);
        const float pw = exp2f(0.852f * __log2f(aq));   // |q|^0.852
        const float fr = Rcoef[ee] * q * pw;
        const float t = (hs[j] - hd[j]) - fr;
        head += (double)t * (double)t;
    }

    #pragma unroll
    for (int off = 32; off >= 1; off >>= 1)
        head += __shfl_down(head, off, 64);
    if ((threadIdx.x & 63) == 0) wsum[threadIdx.x >> 6] = head;
    __syncthreads();
    if (threadIdx.x == 0)
        headp[(size_t)blockIdx.y * gridDim.x + blockIdx.x] =
            wsum[0] + wsum[1] + wsum[2] + wsum[3];
}

// ---------------------------------------------------------------------------
// K3: ONE WAVE PER NODE; 8 row-gathers in flight; mass loss fused via TD.
// Block partial -> PLAIN STORE to massp[block].
// ---------------------------------------------------------------------------
__global__ __launch_bounds__(256) void k_nodemass(
        const __half* __restrict__ QT,      // [E][256]
        const __half* __restrict__ TD,      // [N][256]
        const int* __restrict__ offsets,    // [N+1]
        const int* __restrict__ inc,        // [2E]
        double* __restrict__ massp,         // [(N+3)/4] partials
        int N) {
    __shared__ double wsum[4];
    const int w = threadIdx.x >> 6;
    const int lane = threadIdx.x & 63;
    const int n = blockIdx.x * 4 + w;

    double m = 0.0;
    if (n < N) {
        const uint2 tdr = *reinterpret_cast<const uint2*>(
            (const char*)TD + (size_t)n * 512 + (size_t)lane * 8);

        const int beg = offsets[n];
        const int end = offsets[n + 1];

        float qn0 = 0.f, qn1 = 0.f, qn2 = 0.f, qn3 = 0.f;
        for (int k = beg; k < end; k += 8) {
            int   ivv[8];
            float sg[8];
            uint2 vv[8];
            #pragma unroll
            for (int u = 0; u < 8; ++u) {
                const int kk = (k + u < end) ? (k + u) : (end - 1);
                ivv[u] = inc[kk];                       // wave-uniform bcast
                sg[u] = (k + u < end) ? ((ivv[u] & 1) ? 1.f : -1.f) : 0.f;
                vv[u] = *reinterpret_cast<const uint2*>(
                    (const char*)QT + (size_t)(ivv[u] >> 1) * 512
                                    + (size_t)lane * 8);
            }
            #pragma unroll
            for (int u = 0; u < 8; ++u) {
                const __half2 a = *reinterpret_cast<const __half2*>(&vv[u].x);
                const __half2 b = *reinterpret_cast<const __half2*>(&vv[u].y);
                const float2 fa = __half22float2(a);
                const float2 fb = __half22float2(b);
                qn0 += sg[u] * fa.x; qn1 += sg[u] * fa.y;
                qn2 += sg[u] * fb.x; qn3 += sg[u] * fb.y;
            }
        }

        const __half2 d01 = *reinterpret_cast<const __half2*>(&tdr.x);
        const __half2 d23 = *reinterpret_cast<const __half2*>(&tdr.y);
        const float2 f01 = __half22float2(d01);
        const float2 f23 = __half22float2(d23);
        const float t0 = qn0 - f01.x;
        const float t1 = qn1 - f01.y;
        const float t2 = qn2 - f23.x;
        const float t3 = qn3 - f23.y;
        m = (double)t0 * t0 + (double)t1 * t1
          + (double)t2 * t2 + (double)t3 * t3;
    }

    #pragma unroll
    for (int off = 32; off >= 1; off >>= 1)
        m += __shfl_down(m, off, 64);
    if (lane == 0) wsum[w] = m;
    __syncthreads();
    if (threadIdx.x == 0)
        massp[blockIdx.x] = wsum[0] + wsum[1] + wsum[2] + wsum[3];
}

// ---------------------------------------------------------------------------
// K4: single-block reduction of both partial arrays -> final outputs.
// ---------------------------------------------------------------------------
__global__ void k_reduce(const double* __restrict__ massp, int nm,
                         const double* __restrict__ headp, int nh,
                         float* __restrict__ out,
                         double inv_mass, double inv_head) {
    __shared__ double sh[256];
    const int t = threadIdx.x;

    double s = 0.0;
    for (int i = t; i < nm; i += 256) s += massp[i];
    sh[t] = s;
    __syncthreads();
    #pragma unroll
    for (int off = 128; off >= 1; off >>= 1) {
        if (t < off) sh[t] += sh[t + off];
        __syncthreads();
    }
    double mass_total = 0.0;
    if (t == 0) mass_total = sh[0];
    __syncthreads();

    s = 0.0;
    for (int i = t; i < nh; i += 256) s += headp[i];
    sh[t] = s;
    __syncthreads();
    #pragma unroll
    for (int off = 128; off >= 1; off >>= 1) {
        if (t < off) sh[t] += sh[t + off];
        __syncthreads();
    }
    if (t == 0) {
        out[0] = (float)(mass_total * inv_mass);
        out[1] = (float)(sh[0] * inv_head);
    }
}

static inline size_t align256s(size_t x) { return (x + 255) & ~(size_t)255; }

extern "C" void kernel_launch(void* const* d_in, const int* in_sizes, int n_in,
                              void* d_out, int out_size, void* d_ws, size_t ws_size,
                              hipStream_t stream) {
    const float* pred_p  = (const float*)d_in[0];
    const float* pred_f  = (const float*)d_in[1];
    const float* true_d  = (const float*)d_in[2];
    const float* p_mean  = (const float*)d_in[3];
    const float* p_scale = (const float*)d_in[4];
    const float* f_mean  = (const float*)d_in[5];
    const float* f_scale = (const float*)d_in[6];
    const float* d_mean  = (const float*)d_in[7];
    const float* d_scale = (const float*)d_in[8];
    const float* elev    = (const float*)d_in[9];
    const float* Rcoef   = (const float*)d_in[10];
    const int*   eidx    = (const int*)d_in[11];

    const int N = in_sizes[3];              // 50000
    const int E = in_sizes[10];             // 128000
    const int B = in_sizes[0] / N;          // 256

    const int* esrc = eidx;
    const int* edst = eidx + E;

    const int gn = (N + TILE - 1) / TILE;   // 782
    const int gb = B / TILE;                // 4
    const int ge = E / TILE;                // 2000
    const int nbk = (N + 255) / 256;        // 196
    const int nmB = (N + 3) / 4;            // 12500 nodemass blocks

    // workspace layout
    char* ws = (char*)d_ws;
    size_t off = 0;
    __half* HTh   = (__half*)(ws + off); off = align256s(off + (size_t)N * B * 2);
    __half* TD    = (__half*)(ws + off); off = align256s(off + (size_t)N * B * 2);
    __half* QT    = (__half*)(ws + off); off = align256s(off + (size_t)E * B * 2);
    int* incarr   = (int*)(ws + off);    off = align256s(off + (size_t)2 * E * 4);
    int* offsets  = (int*)(ws + off);    off = align256s(off + (size_t)(N + 1) * 4);
    int* cursor   = (int*)(ws + off);    off = align256s(off + (size_t)N * 4);
    double* headp = (double*)(ws + off); off = align256s(off + (size_t)ge * gb * 8);
    double* massp = (double*)(ws + off); off = align256s(off + (size_t)nmB * 8);
    const size_t zero_beg = off;
    int* deg      = (int*)(ws + off);    off = align256s(off + (size_t)N * 4);
    int* bsum     = (int*)(ws + off);    off = align256s(off + 256 * 4);
    const size_t zero_len = off - zero_beg;

    hipMemsetAsync(ws + zero_beg, 0, zero_len, stream);

    k_hist <<<(2 * E + 255) / 256, 256, 0, stream>>>(eidx, deg, 2 * E);
    k_scan1<<<nbk, 256, 0, stream>>>(deg, bsum, N);
    k_scan2<<<1, 256, 0, stream>>>(bsum, nbk);
    k_scan3<<<nbk, 256, 0, stream>>>(deg, bsum, offsets, cursor, N);
    k_fill <<<(E + 255) / 256, 256, 0, stream>>>(esrc, edst, cursor, incarr, E);

    k_build_ht<<<dim3(gn, gb), 256, 0, stream>>>(pred_p, p_scale, p_mean, elev,
                                                 true_d, d_scale, d_mean,
                                                 HTh, TD, B, N);
    k_edges<<<dim3(ge, gb), 256, 0, stream>>>(pred_f, f_scale, f_mean, Rcoef,
                                              esrc, edst, HTh, QT,
                                              headp, B, E);
    k_nodemass<<<nmB, 256, 0, stream>>>(QT, TD, offsets, incarr, massp, N);
    k_reduce<<<1, 256, 0, stream>>>(massp, nmB, headp, ge * gb,
                                    (float*)d_out,
                                    1.0 / ((double)B * (double)N),
                                    1.0 / ((double)B * (double)E));
}

// Round 18
// 176.227 us; speedup vs baseline: 4.5309x; 1.0268x over previous
//
#include <hip/hip_runtime.h>
#include <hip/hip_fp16.h>

#define TILE 64

// ---------------------------------------------------------------------------
// K1: HTh[n*B+b] = fp16(pred_p*p_scale+p_mean+elev)   (transposed)
//     TD [n*B+b] = fp16(true_d*d_scale+d_mean)        (transposed)
// Also folds the CSR degree histogram (first 2E/256 flat blocks).
// ---------------------------------------------------------------------------
__global__ void k_build_ht(const float* __restrict__ pred_p,
                           const float* __restrict__ p_scale,
                           const float* __restrict__ p_mean,
                           const float* __restrict__ elev,
                           const float* __restrict__ true_d,
                           const float* __restrict__ d_scale,
                           const float* __restrict__ d_mean,
                           const int* __restrict__ nodes,   // eidx flat [2E]
                           int* __restrict__ deg,
                           int M,                           // 2E
                           __half* __restrict__ HTh,
                           __half* __restrict__ TD,
                           int B, int N) {
    __shared__ __align__(16) float tile[TILE][TILE + 2];
    const int n0 = blockIdx.x * TILE;
    const int b0 = blockIdx.y * TILE;
    const int tn = threadIdx.x % TILE;
    const int tw = threadIdx.x / TILE;
    const int c  = threadIdx.x & 31;
    const int rg = threadIdx.x >> 5;
    const int n = n0 + tn;

    // folded histogram (overlaps with staging below)
    const int flat = blockIdx.y * gridDim.x + blockIdx.x;
    if (flat < (M + 255) / 256) {
        const int i = flat * 256 + threadIdx.x;
        if (i < M) atomicAdd(&deg[nodes[i]], 1);
    }

    // ---- pass 1: HT ----
    {
        float sc = 0.f, mn = 0.f, el = 0.f;
        if (n < N) { sc = p_scale[n]; mn = p_mean[n]; el = elev[n]; }
        #pragma unroll
        for (int i = 0; i < TILE / 4; ++i) {
            const int bl = i * 4 + tw;
            float v = 0.f;
            if (n < N) v = pred_p[(size_t)(b0 + bl) * N + n] * sc + mn + el;
            tile[tn][bl] = v;
        }
        __syncthreads();
        #pragma unroll
        for (int i = 0; i < 8; ++i) {
            const int nl = i * 8 + rg;
            const int nn = n0 + nl;
            if (nn < N) {
                const float2 f = *reinterpret_cast<const float2*>(&tile[nl][2 * c]);
                reinterpret_cast<__half2*>(HTh + (size_t)nn * B + b0)[c] =
                    __floats2half2_rn(f.x, f.y);
            }
        }
    }
    __syncthreads();
    // ---- pass 2: TD ----
    {
        float sc = 0.f, mn = 0.f;
        if (n < N) { sc = d_scale[n]; mn = d_mean[n]; }
        #pragma unroll
        for (int i = 0; i < TILE / 4; ++i) {
            const int bl = i * 4 + tw;
            float v = 0.f;
            if (n < N) v = true_d[(size_t)(b0 + bl) * N + n] * sc + mn;
            tile[tn][bl] = v;
        }
        __syncthreads();
        #pragma unroll
        for (int i = 0; i < 8; ++i) {
            const int nl = i * 8 + rg;
            const int nn = n0 + nl;
            if (nn < N) {
                const float2 f = *reinterpret_cast<const float2*>(&tile[nl][2 * c]);
                reinterpret_cast<__half2*>(TD + (size_t)nn * B + b0)[c] =
                    __floats2half2_rn(f.x, f.y);
            }
        }
    }
}

// ---------------------------------------------------------------------------
// CSR scans + fill.  inc[slot] = (edge<<1) | is_dst.
// ---------------------------------------------------------------------------
__global__ void k_scan1(const int* __restrict__ deg, int* __restrict__ bsum, int N) {
    __shared__ int s[256];
    const int i = blockIdx.x * 256 + threadIdx.x;
    s[threadIdx.x] = (i < N) ? deg[i] : 0;
    __syncthreads();
    #pragma unroll
    for (int off = 128; off >= 1; off >>= 1) {
        if (threadIdx.x < off) s[threadIdx.x] += s[threadIdx.x + off];
        __syncthreads();
    }
    if (threadIdx.x == 0) bsum[blockIdx.x] = s[0];
}

__global__ void k_scan2(int* __restrict__ bsum, int nb) {   // 1 block
    __shared__ int s[256];
    const int t = threadIdx.x;
    const int v = (t < nb) ? bsum[t] : 0;
    s[t] = v;
    __syncthreads();
    #pragma unroll
    for (int off = 1; off < 256; off <<= 1) {
        const int tmp = (t >= off) ? s[t - off] : 0;
        __syncthreads();
        s[t] += tmp;
        __syncthreads();
    }
    if (t < nb) bsum[t] = s[t] - v;
}

__global__ void k_scan3(const int* __restrict__ deg, const int* __restrict__ bsum,
                        int* __restrict__ offsets, int* __restrict__ cursor, int N) {
    __shared__ int s[256];
    const int t = threadIdx.x;
    const int i = blockIdx.x * 256 + t;
    const int v = (i < N) ? deg[i] : 0;
    s[t] = v;
    __syncthreads();
    #pragma unroll
    for (int off = 1; off < 256; off <<= 1) {
        const int tmp = (t >= off) ? s[t - off] : 0;
        __syncthreads();
        s[t] += tmp;
        __syncthreads();
    }
    const int excl = s[t] - v + bsum[blockIdx.x];
    if (i < N) { offsets[i] = excl; cursor[i] = excl; }
    if (i == N - 1) offsets[N] = excl + v;
}

__global__ void k_fill(const int* __restrict__ esrc, const int* __restrict__ edst,
                       int* __restrict__ cursor, int* __restrict__ inc, int E) {
    const int e = blockIdx.x * 256 + threadIdx.x;
    if (e < E) {
        const int ps = atomicAdd(&cursor[esrc[e]], 1);
        inc[ps] = (e << 1);            // outflow: -Q
        const int pd = atomicAdd(&cursor[edst[e]], 1);
        inc[pd] = (e << 1) | 1;        // inflow: +Q
    }
}

// ---------------------------------------------------------------------------
// K2 (single-pass): block = 64 edges x ALL 256 batches.
//   stage Q -> fp16 LDS [64][268] (pad 268 halves = 536B rows: all phases
//   conflict-free);  per edge: 1 ds_read_b64 -> 1 QT row store (512B/wave),
//   2 HT row gathers (8B/lane, hoisted 32-deep);  head loss VALU;
//   block partial -> plain store headp[block].
// ---------------------------------------------------------------------------
__global__ __launch_bounds__(256) void k_edges(
        const float* __restrict__ pred_f,
        const float* __restrict__ f_scale,
        const float* __restrict__ f_mean,
        const float* __restrict__ Rcoef,
        const int* __restrict__ esrc,
        const int* __restrict__ edst,
        const __half* __restrict__ HTh,   // [N][256] fp16 (512B rows)
        __half* __restrict__ QT,          // [E][256] fp16 (512B rows)
        double* __restrict__ headp,       // [ge] partials
        int E) {
    __shared__ __align__(16) float tile[TILE][TILE + 2];   // 16.9 KB
    __shared__ __align__(16) __half qth[TILE][268];        // 34.3 KB
    __shared__ double wsum[4];
    const int e0 = blockIdx.x * TILE;
    const int tn = threadIdx.x & 63;     // lane
    const int tw = threadIdx.x >> 6;     // wave
    const int c  = threadIdx.x & 31;
    const int rg = threadIdx.x >> 5;

    const int e = e0 + tn;
    const float fs = f_scale[e];
    const float fm = f_mean[e];

    // ---- stage Q: 4 sub-tiles of 64 batches, transposed into qth[e][b] ----
    for (int sb = 0; sb < 4; ++sb) {
        #pragma unroll
        for (int i = 0; i < 16; ++i) {
            const int bl = i * 4 + tw;
            tile[tn][bl] = pred_f[(size_t)(sb * 64 + bl) * E + e] * fs + fm;
        }
        __syncthreads();
        #pragma unroll
        for (int i = 0; i < 8; ++i) {
            const int el = i * 8 + rg;
            const float2 f2 = *reinterpret_cast<const float2*>(&tile[el][2 * c]);
            *reinterpret_cast<__half2*>(&qth[el][sb * 64 + 2 * c]) =
                __floats2half2_rn(f2.x, f2.y);
        }
        __syncthreads();
    }

    // ---- loop1: QT row store + issue all 32 gathers ----
    uint2 hsv[16], hdv[16];
    float Rv[16];
    #pragma unroll
    for (int j = 0; j < 16; ++j) {
        const int el = tw * 16 + j;
        const int ee = e0 + el;
        const int s = esrc[ee];
        const int d = edst[ee];
        Rv[j] = Rcoef[ee];
        hsv[j] = *reinterpret_cast<const uint2*>(
            (const char*)HTh + (size_t)s * 512 + (size_t)tn * 8);
        hdv[j] = *reinterpret_cast<const uint2*>(
            (const char*)HTh + (size_t)d * 512 + (size_t)tn * 8);
        const uint2 q4 = *reinterpret_cast<const uint2*>(
            (const char*)&qth[el][0] + (size_t)tn * 8);
        *reinterpret_cast<uint2*>(
            (char*)QT + (size_t)ee * 512 + (size_t)tn * 8) = q4;
    }

    // ---- loop2: head loss (4 batches per lane per edge) ----
    double head = 0.0;
    #pragma unroll
    for (int j = 0; j < 16; ++j) {
        const int el = tw * 16 + j;
        const uint2 q4 = *reinterpret_cast<const uint2*>(
            (const char*)&qth[el][0] + (size_t)tn * 8);
        const __half2 qa = *reinterpret_cast<const __half2*>(&q4.x);
        const __half2 qb = *reinterpret_cast<const __half2*>(&q4.y);
        const __half2 sa = *reinterpret_cast<const __half2*>(&hsv[j].x);
        const __half2 sb2 = *reinterpret_cast<const __half2*>(&hsv[j].y);
        const __half2 da = *reinterpret_cast<const __half2*>(&hdv[j].x);
        const __half2 db = *reinterpret_cast<const __half2*>(&hdv[j].y);
        const float2 qf0 = __half22float2(qa), qf1 = __half22float2(qb);
        const float2 sf0 = __half22float2(sa), sf1 = __half22float2(sb2);
        const float2 df0 = __half22float2(da), df1 = __half22float2(db);
        const float R = Rv[j];

        float qv[4] = {qf0.x, qf0.y, qf1.x, qf1.y};
        float sv[4] = {sf0.x, sf0.y, sf1.x, sf1.y};
        float dv[4] = {df0.x, df0.y, df1.x, df1.y};
        #pragma unroll
        for (int r = 0; r < 4; ++r) {
            const float q = qv[r];
            const float aq = fabsf(q);
            const float pw = exp2f(0.852f * __log2f(aq));   // |q|^0.852
            const float fr = R * q * pw;
            const float t = (sv[r] - dv[r]) - fr;
            head += (double)t * (double)t;
        }
    }

    #pragma unroll
    for (int off = 32; off >= 1; off >>= 1)
        head += __shfl_down(head, off, 64);
    if ((threadIdx.x & 63) == 0) wsum[threadIdx.x >> 6] = head;
    __syncthreads();
    if (threadIdx.x == 0)
        headp[blockIdx.x] = wsum[0] + wsum[1] + wsum[2] + wsum[3];
}

// ---------------------------------------------------------------------------
// K3: ONE WAVE PER NODE; row-gathers hoisted; deg<=4 fast path; mass loss
// fused via TD.  Block partial -> plain store massp[block].
// ---------------------------------------------------------------------------
__global__ __launch_bounds__(256) void k_nodemass(
        const __half* __restrict__ QT,      // [E][256]
        const __half* __restrict__ TD,      // [N][256]
        const int* __restrict__ offsets,    // [N+1]
        const int* __restrict__ inc,        // [2E]
        double* __restrict__ massp,         // [(N+3)/4] partials
        int N) {
    __shared__ double wsum[4];
    const int w = threadIdx.x >> 6;
    const int lane = threadIdx.x & 63;
    const int n = blockIdx.x * 4 + w;

    double m = 0.0;
    if (n < N) {
        const uint2 tdr = *reinterpret_cast<const uint2*>(
            (const char*)TD + (size_t)n * 512 + (size_t)lane * 8);

        const int beg = offsets[n];
        const int end = offsets[n + 1];
        const int cnt = end - beg;

        float qn0 = 0.f, qn1 = 0.f, qn2 = 0.f, qn3 = 0.f;
        if (cnt <= 4) {
            int   ivv[4];
            float sg[4];
            uint2 vv[4];
            #pragma unroll
            for (int u = 0; u < 4; ++u) {
                const int kk = (beg + u < end) ? (beg + u) : (end - 1);
                ivv[u] = inc[kk];
                sg[u] = (beg + u < end) ? ((ivv[u] & 1) ? 1.f : -1.f) : 0.f;
                vv[u] = *reinterpret_cast<const uint2*>(
                    (const char*)QT + (size_t)(ivv[u] >> 1) * 512
                                    + (size_t)lane * 8);
            }
            #pragma unroll
            for (int u = 0; u < 4; ++u) {
                const __half2 a = *reinterpret_cast<const __half2*>(&vv[u].x);
                const __half2 b = *reinterpret_cast<const __half2*>(&vv[u].y);
                const float2 fa = __half22float2(a);
                const float2 fb = __half22float2(b);
                qn0 += sg[u] * fa.x; qn1 += sg[u] * fa.y;
                qn2 += sg[u] * fb.x; qn3 += sg[u] * fb.y;
            }
        } else {
            for (int k = beg; k < end; k += 8) {
                int   ivv[8];
                float sg[8];
                uint2 vv[8];
                #pragma unroll
                for (int u = 0; u < 8; ++u) {
                    const int kk = (k + u < end) ? (k + u) : (end - 1);
                    ivv[u] = inc[kk];
                    sg[u] = (k + u < end) ? ((ivv[u] & 1) ? 1.f : -1.f) : 0.f;
                    vv[u] = *reinterpret_cast<const uint2*>(
                        (const char*)QT + (size_t)(ivv[u] >> 1) * 512
                                        + (size_t)lane * 8);
                }
                #pragma unroll
                for (int u = 0; u < 8; ++u) {
                    const __half2 a = *reinterpret_cast<const __half2*>(&vv[u].x);
                    const __half2 b = *reinterpret_cast<const __half2*>(&vv[u].y);
                    const float2 fa = __half22float2(a);
                    const float2 fb = __half22float2(b);
                    qn0 += sg[u] * fa.x; qn1 += sg[u] * fa.y;
                    qn2 += sg[u] * fb.x; qn3 += sg[u] * fb.y;
                }
            }
        }

        const __half2 d01 = *reinterpret_cast<const __half2*>(&tdr.x);
        const __half2 d23 = *reinterpret_cast<const __half2*>(&tdr.y);
        const float2 f01 = __half22float2(d01);
        const float2 f23 = __half22float2(d23);
        const float t0 = qn0 - f01.x;
        const float t1 = qn1 - f01.y;
        const float t2 = qn2 - f23.x;
        const float t3 = qn3 - f23.y;
        m = (double)t0 * t0 + (double)t1 * t1
          + (double)t2 * t2 + (double)t3 * t3;
    }

    #pragma unroll
    for (int off = 32; off >= 1; off >>= 1)
        m += __shfl_down(m, off, 64);
    if (lane == 0) wsum[w] = m;
    __syncthreads();
    if (threadIdx.x == 0)
        massp[blockIdx.x] = wsum[0] + wsum[1] + wsum[2] + wsum[3];
}

// ---------------------------------------------------------------------------
// K4: single-block reduction of both partial arrays -> final outputs.
// ---------------------------------------------------------------------------
__global__ void k_reduce(const double* __restrict__ massp, int nm,
                         const double* __restrict__ headp, int nh,
                         float* __restrict__ out,
                         double inv_mass, double inv_head) {
    __shared__ double sh[256];
    const int t = threadIdx.x;

    double s = 0.0;
    for (int i = t; i < nm; i += 256) s += massp[i];
    sh[t] = s;
    __syncthreads();
    #pragma unroll
    for (int off = 128; off >= 1; off >>= 1) {
        if (t < off) sh[t] += sh[t + off];
        __syncthreads();
    }
    double mass_total = 0.0;
    if (t == 0) mass_total = sh[0];
    __syncthreads();

    s = 0.0;
    for (int i = t; i < nh; i += 256) s += headp[i];
    sh[t] = s;
    __syncthreads();
    #pragma unroll
    for (int off = 128; off >= 1; off >>= 1) {
        if (t < off) sh[t] += sh[t + off];
        __syncthreads();
    }
    if (t == 0) {
        out[0] = (float)(mass_total * inv_mass);
        out[1] = (float)(sh[0] * inv_head);
    }
}

static inline size_t align256s(size_t x) { return (x + 255) & ~(size_t)255; }

extern "C" void kernel_launch(void* const* d_in, const int* in_sizes, int n_in,
                              void* d_out, int out_size, void* d_ws, size_t ws_size,
                              hipStream_t stream) {
    const float* pred_p  = (const float*)d_in[0];
    const float* pred_f  = (const float*)d_in[1];
    const float* true_d  = (const float*)d_in[2];
    const float* p_mean  = (const float*)d_in[3];
    const float* p_scale = (const float*)d_in[4];
    const float* f_mean  = (const float*)d_in[5];
    const float* f_scale = (const float*)d_in[6];
    const float* d_mean  = (const float*)d_in[7];
    const float* d_scale = (const float*)d_in[8];
    const float* elev    = (const float*)d_in[9];
    const float* Rcoef   = (const float*)d_in[10];
    const int*   eidx    = (const int*)d_in[11];

    const int N = in_sizes[3];              // 50000
    const int E = in_sizes[10];             // 128000
    const int B = in_sizes[0] / N;          // 256

    const int* esrc = eidx;
    const int* edst = eidx + E;

    const int gn = (N + TILE - 1) / TILE;   // 782
    const int gb = B / TILE;                // 4
    const int ge = E / TILE;                // 2000
    const int nbk = (N + 255) / 256;        // 196
    const int nmB = (N + 3) / 4;            // 12500 nodemass blocks

    // workspace layout
    char* ws = (char*)d_ws;
    size_t off = 0;
    __half* HTh   = (__half*)(ws + off); off = align256s(off + (size_t)N * B * 2);
    __half* TD    = (__half*)(ws + off); off = align256s(off + (size_t)N * B * 2);
    __half* QT    = (__half*)(ws + off); off = align256s(off + (size_t)E * B * 2);
    int* incarr   = (int*)(ws + off);    off = align256s(off + (size_t)2 * E * 4);
    int* offsets  = (int*)(ws + off);    off = align256s(off + (size_t)(N + 1) * 4);
    int* cursor   = (int*)(ws + off);    off = align256s(off + (size_t)N * 4);
    double* headp = (double*)(ws + off); off = align256s(off + (size_t)ge * 8);
    double* massp = (double*)(ws + off); off = align256s(off + (size_t)nmB * 8);
    const size_t zero_beg = off;
    int* deg      = (int*)(ws + off);    off = align256s(off + (size_t)N * 4);
    int* bsum     = (int*)(ws + off);    off = align256s(off + 256 * 4);
    const size_t zero_len = off - zero_beg;

    hipMemsetAsync(ws + zero_beg, 0, zero_len, stream);

    // build_ht also does the degree histogram (deg zeroed above)
    k_build_ht<<<dim3(gn, gb), 256, 0, stream>>>(pred_p, p_scale, p_mean, elev,
                                                 true_d, d_scale, d_mean,
                                                 eidx, deg, 2 * E,
                                                 HTh, TD, B, N);
    k_scan1<<<nbk, 256, 0, stream>>>(deg, bsum, N);
    k_scan2<<<1, 256, 0, stream>>>(bsum, nbk);
    k_scan3<<<nbk, 256, 0, stream>>>(deg, bsum, offsets, cursor, N);
    k_fill <<<(E + 255) / 256, 256, 0, stream>>>(esrc, edst, cursor, incarr, E);

    k_edges<<<ge, 256, 0, stream>>>(pred_f, f_scale, f_mean, Rcoef,
                                    esrc, edst, HTh, QT, headp, E);
    k_nodemass<<<nmB, 256, 0, stream>>>(QT, TD, offsets, incarr, massp, N);
    k_reduce<<<1, 256, 0, stream>>>(massp, nmB, headp, ge,
                                    (float*)d_out,
                                    1.0 / ((double)B * (double)N),
                                    1.0 / ((double)B * (double)E));
}

// Round 19
// 175.792 us; speedup vs baseline: 4.5421x; 1.0025x over previous
//
#include <hip/hip_runtime.h>
#include <hip/hip_fp16.h>

#define TILE 64

// ---------------------------------------------------------------------------
// K1: HTh[n*B+b] = fp16(pred_p*p_scale+p_mean+elev)   (transposed)
//     TD [n*B+b] = fp16(true_d*d_scale+d_mean)        (transposed)
// Also folds the CSR degree histogram (first 2E/256 flat blocks).
// ---------------------------------------------------------------------------
__global__ void k_build_ht(const float* __restrict__ pred_p,
                           const float* __restrict__ p_scale,
                           const float* __restrict__ p_mean,
                           const float* __restrict__ elev,
                           const float* __restrict__ true_d,
                           const float* __restrict__ d_scale,
                           const float* __restrict__ d_mean,
                           const int* __restrict__ nodes,   // eidx flat [2E]
                           int* __restrict__ deg,
                           int M,                           // 2E
                           __half* __restrict__ HTh,
                           __half* __restrict__ TD,
                           int B, int N) {
    __shared__ __align__(16) float tile[TILE][TILE + 2];
    const int n0 = blockIdx.x * TILE;
    const int b0 = blockIdx.y * TILE;
    const int tn = threadIdx.x % TILE;
    const int tw = threadIdx.x / TILE;
    const int c  = threadIdx.x & 31;
    const int rg = threadIdx.x >> 5;
    const int n = n0 + tn;

    // folded histogram (overlaps with staging below)
    const int flat = blockIdx.y * gridDim.x + blockIdx.x;
    if (flat < (M + 255) / 256) {
        const int i = flat * 256 + threadIdx.x;
        if (i < M) atomicAdd(&deg[nodes[i]], 1);
    }

    // ---- pass 1: HT ----
    {
        float sc = 0.f, mn = 0.f, el = 0.f;
        if (n < N) { sc = p_scale[n]; mn = p_mean[n]; el = elev[n]; }
        #pragma unroll
        for (int i = 0; i < TILE / 4; ++i) {
            const int bl = i * 4 + tw;
            float v = 0.f;
            if (n < N) v = pred_p[(size_t)(b0 + bl) * N + n] * sc + mn + el;
            tile[tn][bl] = v;
        }
        __syncthreads();
        #pragma unroll
        for (int i = 0; i < 8; ++i) {
            const int nl = i * 8 + rg;
            const int nn = n0 + nl;
            if (nn < N) {
                const float2 f = *reinterpret_cast<const float2*>(&tile[nl][2 * c]);
                reinterpret_cast<__half2*>(HTh + (size_t)nn * B + b0)[c] =
                    __floats2half2_rn(f.x, f.y);
            }
        }
    }
    __syncthreads();
    // ---- pass 2: TD ----
    {
        float sc = 0.f, mn = 0.f;
        if (n < N) { sc = d_scale[n]; mn = d_mean[n]; }
        #pragma unroll
        for (int i = 0; i < TILE / 4; ++i) {
            const int bl = i * 4 + tw;
            float v = 0.f;
            if (n < N) v = true_d[(size_t)(b0 + bl) * N + n] * sc + mn;
            tile[tn][bl] = v;
        }
        __syncthreads();
        #pragma unroll
        for (int i = 0; i < 8; ++i) {
            const int nl = i * 8 + rg;
            const int nn = n0 + nl;
            if (nn < N) {
                const float2 f = *reinterpret_cast<const float2*>(&tile[nl][2 * c]);
                reinterpret_cast<__half2*>(TD + (size_t)nn * B + b0)[c] =
                    __floats2half2_rn(f.x, f.y);
            }
        }
    }
}

// ---------------------------------------------------------------------------
// CSR scans + fill.  inc[slot] = (edge<<1) | is_dst.
// ---------------------------------------------------------------------------
__global__ void k_scan1(const int* __restrict__ deg, int* __restrict__ bsum, int N) {
    __shared__ int s[256];
    const int i = blockIdx.x * 256 + threadIdx.x;
    s[threadIdx.x] = (i < N) ? deg[i] : 0;
    __syncthreads();
    #pragma unroll
    for (int off = 128; off >= 1; off >>= 1) {
        if (threadIdx.x < off) s[threadIdx.x] += s[threadIdx.x + off];
        __syncthreads();
    }
    if (threadIdx.x == 0) bsum[blockIdx.x] = s[0];
}

__global__ void k_scan2(int* __restrict__ bsum, int nb) {   // 1 block
    __shared__ int s[256];
    const int t = threadIdx.x;
    const int v = (t < nb) ? bsum[t] : 0;
    s[t] = v;
    __syncthreads();
    #pragma unroll
    for (int off = 1; off < 256; off <<= 1) {
        const int tmp = (t >= off) ? s[t - off] : 0;
        __syncthreads();
        s[t] += tmp;
        __syncthreads();
    }
    if (t < nb) bsum[t] = s[t] - v;
}

__global__ void k_scan3(const int* __restrict__ deg, const int* __restrict__ bsum,
                        int* __restrict__ offsets, int* __restrict__ cursor, int N) {
    __shared__ int s[256];
    const int t = threadIdx.x;
    const int i = blockIdx.x * 256 + t;
    const int v = (i < N) ? deg[i] : 0;
    s[t] = v;
    __syncthreads();
    #pragma unroll
    for (int off = 1; off < 256; off <<= 1) {
        const int tmp = (t >= off) ? s[t - off] : 0;
        __syncthreads();
        s[t] += tmp;
        __syncthreads();
    }
    const int excl = s[t] - v + bsum[blockIdx.x];
    if (i < N) { offsets[i] = excl; cursor[i] = excl; }
    if (i == N - 1) offsets[N] = excl + v;
}

__global__ void k_fill(const int* __restrict__ esrc, const int* __restrict__ edst,
                       int* __restrict__ cursor, int* __restrict__ inc, int E) {
    const int e = blockIdx.x * 256 + threadIdx.x;
    if (e < E) {
        const int ps = atomicAdd(&cursor[esrc[e]], 1);
        inc[ps] = (e << 1);            // outflow: -Q
        const int pd = atomicAdd(&cursor[edst[e]], 1);
        inc[pd] = (e << 1) | 1;        // inflow: +Q
    }
}

// ---------------------------------------------------------------------------
// K2 (single-pass): block = 64 edges x ALL 256 batches.
//   Stage Q DIRECTLY as fp16 into qth[64][258] (lane=edge, col=batch — no
//   transpose tile, one barrier; row=516B=129 words => staged writes hit
//   bank (tn mod 32): 2-way = free).  Per edge: 1 ds_read_b64 -> 1 QT row
//   store (512B/wave), 2 HT row gathers (8B/lane, hoisted 32-deep); head
//   loss VALU; block partial -> plain store headp[block].
// ---------------------------------------------------------------------------
__global__ __launch_bounds__(256) void k_edges(
        const float* __restrict__ pred_f,
        const float* __restrict__ f_scale,
        const float* __restrict__ f_mean,
        const float* __restrict__ Rcoef,
        const int* __restrict__ esrc,
        const int* __restrict__ edst,
        const __half* __restrict__ HTh,   // [N][256] fp16 (512B rows)
        __half* __restrict__ QT,          // [E][256] fp16 (512B rows)
        double* __restrict__ headp,       // [ge] partials
        int E) {
    __shared__ __align__(16) __half qth[TILE][258];        // 33 KB
    __shared__ double wsum[4];
    const int e0 = blockIdx.x * TILE;
    const int tn = threadIdx.x & 63;     // lane
    const int tw = threadIdx.x >> 6;     // wave

    const int e = e0 + tn;
    const float fs = f_scale[e];
    const float fm = f_mean[e];

    // ---- stage Q directly: lane = edge, column = batch (already edge-major)
    #pragma unroll
    for (int sb = 0; sb < 4; ++sb) {
        #pragma unroll
        for (int i = 0; i < 16; ++i) {
            const int bl = i * 4 + tw;           // batch within sub-tile
            const float v = pred_f[(size_t)(sb * 64 + bl) * E + e] * fs + fm;
            qth[tn][sb * 64 + bl] = __float2half_rn(v);
        }
    }
    __syncthreads();

    // ---- loop1: QT row store + issue all 32 gathers ----
    uint2 hsv[16], hdv[16];
    float Rv[16];
    #pragma unroll
    for (int j = 0; j < 16; ++j) {
        const int el = tw * 16 + j;
        const int ee = e0 + el;
        const int s = esrc[ee];
        const int d = edst[ee];
        Rv[j] = Rcoef[ee];
        hsv[j] = *reinterpret_cast<const uint2*>(
            (const char*)HTh + (size_t)s * 512 + (size_t)tn * 8);
        hdv[j] = *reinterpret_cast<const uint2*>(
            (const char*)HTh + (size_t)d * 512 + (size_t)tn * 8);
        const uint2 q4 = *reinterpret_cast<const uint2*>(
            (const char*)&qth[el][0] + (size_t)tn * 8);
        *reinterpret_cast<uint2*>(
            (char*)QT + (size_t)ee * 512 + (size_t)tn * 8) = q4;
    }

    // ---- loop2: head loss (4 batches per lane per edge) ----
    double head = 0.0;
    #pragma unroll
    for (int j = 0; j < 16; ++j) {
        const int el = tw * 16 + j;
        const uint2 q4 = *reinterpret_cast<const uint2*>(
            (const char*)&qth[el][0] + (size_t)tn * 8);
        const __half2 qa = *reinterpret_cast<const __half2*>(&q4.x);
        const __half2 qb = *reinterpret_cast<const __half2*>(&q4.y);
        const __half2 sa = *reinterpret_cast<const __half2*>(&hsv[j].x);
        const __half2 sb2 = *reinterpret_cast<const __half2*>(&hsv[j].y);
        const __half2 da = *reinterpret_cast<const __half2*>(&hdv[j].x);
        const __half2 db = *reinterpret_cast<const __half2*>(&hdv[j].y);
        const float2 qf0 = __half22float2(qa), qf1 = __half22float2(qb);
        const float2 sf0 = __half22float2(sa), sf1 = __half22float2(sb2);
        const float2 df0 = __half22float2(da), df1 = __half22float2(db);
        const float R = Rv[j];

        float qv[4] = {qf0.x, qf0.y, qf1.x, qf1.y};
        float sv[4] = {sf0.x, sf0.y, sf1.x, sf1.y};
        float dv[4] = {df0.x, df0.y, df1.x, df1.y};
        #pragma unroll
        for (int r = 0; r < 4; ++r) {
            const float q = qv[r];
            const float aq = fabsf(q);
            const float pw = exp2f(0.852f * __log2f(aq));   // |q|^0.852
            const float fr = R * q * pw;
            const float t = (sv[r] - dv[r]) - fr;
            head += (double)t * (double)t;
        }
    }

    #pragma unroll
    for (int off = 32; off >= 1; off >>= 1)
        head += __shfl_down(head, off, 64);
    if ((threadIdx.x & 63) == 0) wsum[threadIdx.x >> 6] = head;
    __syncthreads();
    if (threadIdx.x == 0)
        headp[blockIdx.x] = wsum[0] + wsum[1] + wsum[2] + wsum[3];
}

// ---------------------------------------------------------------------------
// K3: ONE WAVE PER NODE; row-gathers hoisted; deg<=4 fast path; mass loss
// fused via TD.  Block partial -> plain store massp[block].
// ---------------------------------------------------------------------------
__global__ __launch_bounds__(256) void k_nodemass(
        const __half* __restrict__ QT,      // [E][256]
        const __half* __restrict__ TD,      // [N][256]
        const int* __restrict__ offsets,    // [N+1]
        const int* __restrict__ inc,        // [2E]
        double* __restrict__ massp,         // [(N+3)/4] partials
        int N) {
    __shared__ double wsum[4];
    const int w = threadIdx.x >> 6;
    const int lane = threadIdx.x & 63;
    const int n = blockIdx.x * 4 + w;

    double m = 0.0;
    if (n < N) {
        const uint2 tdr = *reinterpret_cast<const uint2*>(
            (const char*)TD + (size_t)n * 512 + (size_t)lane * 8);

        const int beg = offsets[n];
        const int end = offsets[n + 1];
        const int cnt = end - beg;

        float qn0 = 0.f, qn1 = 0.f, qn2 = 0.f, qn3 = 0.f;
        if (cnt <= 4) {
            int   ivv[4];
            float sg[4];
            uint2 vv[4];
            #pragma unroll
            for (int u = 0; u < 4; ++u) {
                const int kk = (beg + u < end) ? (beg + u) : (end - 1);
                ivv[u] = inc[kk];
                sg[u] = (beg + u < end) ? ((ivv[u] & 1) ? 1.f : -1.f) : 0.f;
                vv[u] = *reinterpret_cast<const uint2*>(
                    (const char*)QT + (size_t)(ivv[u] >> 1) * 512
                                    + (size_t)lane * 8);
            }
            #pragma unroll
            for (int u = 0; u < 4; ++u) {
                const __half2 a = *reinterpret_cast<const __half2*>(&vv[u].x);
                const __half2 b = *reinterpret_cast<const __half2*>(&vv[u].y);
                const float2 fa = __half22float2(a);
                const float2 fb = __half22float2(b);
                qn0 += sg[u] * fa.x; qn1 += sg[u] * fa.y;
                qn2 += sg[u] * fb.x; qn3 += sg[u] * fb.y;
            }
        } else {
            for (int k = beg; k < end; k += 8) {
                int   ivv[8];
                float sg[8];
                uint2 vv[8];
                #pragma unroll
                for (int u = 0; u < 8; ++u) {
                    const int kk = (k + u < end) ? (k + u) : (end - 1);
                    ivv[u] = inc[kk];
                    sg[u] = (k + u < end) ? ((ivv[u] & 1) ? 1.f : -1.f) : 0.f;
                    vv[u] = *reinterpret_cast<const uint2*>(
                        (const char*)QT + (size_t)(ivv[u] >> 1) * 512
                                        + (size_t)lane * 8);
                }
                #pragma unroll
                for (int u = 0; u < 8; ++u) {
                    const __half2 a = *reinterpret_cast<const __half2*>(&vv[u].x);
                    const __half2 b = *reinterpret_cast<const __half2*>(&vv[u].y);
                    const float2 fa = __half22float2(a);
                    const float2 fb = __half22float2(b);
                    qn0 += sg[u] * fa.x; qn1 += sg[u] * fa.y;
                    qn2 += sg[u] * fb.x; qn3 += sg[u] * fb.y;
                }
            }
        }

        const __half2 d01 = *reinterpret_cast<const __half2*>(&tdr.x);
        const __half2 d23 = *reinterpret_cast<const __half2*>(&tdr.y);
        const float2 f01 = __half22float2(d01);
        const float2 f23 = __half22float2(d23);
        const float t0 = qn0 - f01.x;
        const float t1 = qn1 - f01.y;
        const float t2 = qn2 - f23.x;
        const float t3 = qn3 - f23.y;
        m = (double)t0 * t0 + (double)t1 * t1
          + (double)t2 * t2 + (double)t3 * t3;
    }

    #pragma unroll
    for (int off = 32; off >= 1; off >>= 1)
        m += __shfl_down(m, off, 64);
    if (lane == 0) wsum[w] = m;
    __syncthreads();
    if (threadIdx.x == 0)
        massp[blockIdx.x] = wsum[0] + wsum[1] + wsum[2] + wsum[3];
}

// ---------------------------------------------------------------------------
// K4: single-block reduction of both partial arrays -> final outputs.
// ---------------------------------------------------------------------------
__global__ void k_reduce(const double* __restrict__ massp, int nm,
                         const double* __restrict__ headp, int nh,
                         float* __restrict__ out,
                         double inv_mass, double inv_head) {
    __shared__ double sh[256];
    const int t = threadIdx.x;

    double s = 0.0;
    for (int i = t; i < nm; i += 256) s += massp[i];
    sh[t] = s;
    __syncthreads();
    #pragma unroll
    for (int off = 128; off >= 1; off >>= 1) {
        if (t < off) sh[t] += sh[t + off];
        __syncthreads();
    }
    double mass_total = 0.0;
    if (t == 0) mass_total = sh[0];
    __syncthreads();

    s = 0.0;
    for (int i = t; i < nh; i += 256) s += headp[i];
    sh[t] = s;
    __syncthreads();
    #pragma unroll
    for (int off = 128; off >= 1; off >>= 1) {
        if (t < off) sh[t] += sh[t + off];
        __syncthreads();
    }
    if (t == 0) {
        out[0] = (float)(mass_total * inv_mass);
        out[1] = (float)(sh[0] * inv_head);
    }
}

static inline size_t align256s(size_t x) { return (x + 255) & ~(size_t)255; }

extern "C" void kernel_launch(void* const* d_in, const int* in_sizes, int n_in,
                              void* d_out, int out_size, void* d_ws, size_t ws_size,
                              hipStream_t stream) {
    const float* pred_p  = (const float*)d_in[0];
    const float* pred_f  = (const float*)d_in[1];
    const float* true_d  = (const float*)d_in[2];
    const float* p_mean  = (const float*)d_in[3];
    const float* p_scale = (const float*)d_in[4];
    const float* f_mean  = (const float*)d_in[5];
    const float* f_scale = (const float*)d_in[6];
    const float* d_mean  = (const float*)d_in[7];
    const float* d_scale = (const float*)d_in[8];
    const float* elev    = (const float*)d_in[9];
    const float* Rcoef   = (const float*)d_in[10];
    const int*   eidx    = (const int*)d_in[11];

    const int N = in_sizes[3];              // 50000
    const int E = in_sizes[10];             // 128000
    const int B = in_sizes[0] / N;          // 256

    const int* esrc = eidx;
    const int* edst = eidx + E;

    const int gn = (N + TILE - 1) / TILE;   // 782
    const int gb = B / TILE;                // 4
    const int ge = E / TILE;                // 2000
    const int nbk = (N + 255) / 256;        // 196
    const int nmB = (N + 3) / 4;            // 12500 nodemass blocks

    // workspace layout
    char* ws = (char*)d_ws;
    size_t off = 0;
    __half* HTh   = (__half*)(ws + off); off = align256s(off + (size_t)N * B * 2);
    __half* TD    = (__half*)(ws + off); off = align256s(off + (size_t)N * B * 2);
    __half* QT    = (__half*)(ws + off); off = align256s(off + (size_t)E * B * 2);
    int* incarr   = (int*)(ws + off);    off = align256s(off + (size_t)2 * E * 4);
    int* offsets  = (int*)(ws + off);    off = align256s(off + (size_t)(N + 1) * 4);
    int* cursor   = (int*)(ws + off);    off = align256s(off + (size_t)N * 4);
    double* headp = (double*)(ws + off); off = align256s(off + (size_t)ge * 8);
    double* massp = (double*)(ws + off); off = align256s(off + (size_t)nmB * 8);
    const size_t zero_beg = off;
    int* deg      = (int*)(ws + off);    off = align256s(off + (size_t)N * 4);
    int* bsum     = (int*)(ws + off);    off = align256s(off + 256 * 4);
    const size_t zero_len = off - zero_beg;

    hipMemsetAsync(ws + zero_beg, 0, zero_len, stream);

    // build_ht also does the degree histogram (deg zeroed above)
    k_build_ht<<<dim3(gn, gb), 256, 0, stream>>>(pred_p, p_scale, p_mean, elev,
                                                 true_d, d_scale, d_mean,
                                                 eidx, deg, 2 * E,
                                                 HTh, TD, B, N);
    k_scan1<<<nbk, 256, 0, stream>>>(deg, bsum, N);
    k_scan2<<<1, 256, 0, stream>>>(bsum, nbk);
    k_scan3<<<nbk, 256, 0, stream>>>(deg, bsum, offsets, cursor, N);
    k_fill <<<(E + 255) / 256, 256, 0, stream>>>(esrc, edst, cursor, incarr, E);

    k_edges<<<ge, 256, 0, stream>>>(pred_f, f_scale, f_mean, Rcoef,
                                    esrc, edst, HTh, QT, headp, E);
    k_nodemass<<<nmB, 256, 0, stream>>>(QT, TD, offsets, incarr, massp, N);
    k_reduce<<<1, 256, 0, stream>>>(massp, nmB, headp, ge,
                                    (float*)d_out,
                                    1.0 / ((double)B * (double)N),
                                    1.0 / ((double)B * (double)E));
}